// Round 2
// baseline (650.128 us; speedup 1.0000x reference)
//
#include <hip/hip_runtime.h>
#include <hip/hip_bf16.h>

// Problem dims (fixed by setup_inputs)
#define Bb 16
#define Tt 64
#define Nn 512
#define BT (Bb*Tt)      // 1024
#define LH 64
#define Mseq (Bb*Nn)    // 8192

typedef short  bf16x8 __attribute__((ext_vector_type(8)));
typedef float  f32x16 __attribute__((ext_vector_type(16)));
typedef float  f32x4  __attribute__((ext_vector_type(4)));

__device__ __forceinline__ unsigned short f2bf(float f) {
    unsigned int u = __float_as_uint(f);
    return (unsigned short)((u + 0x7FFFu + ((u >> 16) & 1u)) >> 16);
}
__device__ __forceinline__ float bf2f(unsigned short b) {
    return __uint_as_float(((unsigned int)b) << 16);
}
__device__ __forceinline__ void split8(const float* v, bf16x8& hi, bf16x8& lo) {
#pragma unroll
    for (int i = 0; i < 8; ++i) {
        unsigned short h = f2bf(v[i]);
        hi[i] = (short)h;
        lo[i] = (short)f2bf(v[i] - bf2f(h));
    }
}
__device__ __forceinline__ float fget(const float4& v, int q) {
    return q == 0 ? v.x : q == 1 ? v.y : q == 2 ? v.z : v.w;
}
__device__ __forceinline__ float sigf(float x)  { return 1.f / (1.f + __expf(-x)); }
__device__ __forceinline__ float tanhfast(float x) { return 2.f / (1.f + __expf(-2.f * x)) - 1.f; }

// ---------------------------------------------------------------------------
// Kernel A: S[bt][n] = sum_m X[bt][m] * adj[n][m]   (fp32 VALU; ~20us, cheap)
// ---------------------------------------------------------------------------
__global__ __launch_bounds__(256) void sgemm_kernel(
    const float* __restrict__ X, const float* __restrict__ adj,
    float* __restrict__ S)
{
    __shared__ __align__(16) float Xs[64 * 68];
    __shared__ __align__(16) float As[64 * 68];
    const int tid = threadIdx.x;
    const int nb  = blockIdx.x * 64;
    const int bt0 = blockIdx.y * 64;

    const int lr  = tid >> 4;
    const int lc4 = (tid & 15) * 4;
    const int r0  = 4 * (tid >> 4);
    const int c0  = 4 * (tid & 15);

    float acc[4][4] = {};

    for (int kc = 0; kc < 8; ++kc) {
        __syncthreads();
#pragma unroll
        for (int s = 0; s < 64; s += 16) {
            *(float4*)&Xs[(lr + s) * 68 + lc4] =
                *(const float4*)&X[(size_t)(bt0 + lr + s) * Nn + kc * 64 + lc4];
            *(float4*)&As[(lr + s) * 68 + lc4] =
                *(const float4*)&adj[(size_t)(nb + lr + s) * Nn + kc * 64 + lc4];
        }
        __syncthreads();
#pragma unroll 4
        for (int k4 = 0; k4 < 64; k4 += 4) {
            float4 x4[4], a4[4];
#pragma unroll
            for (int i = 0; i < 4; ++i) x4[i] = *(float4*)&Xs[(r0 + i) * 68 + k4];
#pragma unroll
            for (int j = 0; j < 4; ++j) a4[j] = *(float4*)&As[(c0 + j) * 68 + k4];
#pragma unroll
            for (int i = 0; i < 4; ++i)
#pragma unroll
                for (int j = 0; j < 4; ++j)
                    acc[i][j] += x4[i].x * a4[j].x + x4[i].y * a4[j].y +
                                 x4[i].z * a4[j].z + x4[i].w * a4[j].w;
        }
    }
#pragma unroll
    for (int i = 0; i < 4; ++i) {
        float4 v = make_float4(acc[i][0], acc[i][1], acc[i][2], acc[i][3]);
        *(float4*)&S[(size_t)(bt0 + r0 + i) * Nn + nb + c0] = v;
    }
}

// ---------------------------------------------------------------------------
// Kernel B: fused GCN via split-bf16 MFMA.
//   C[n][g]  = sum_m adj[n][m] * relu(S[bt][m]*w1[g] + b1[g])
//   out[n][h]= relu(b2[h] + sum_g C[n][g]*W2[h][g])  -> [m=b*N+n][t][h] layout
// 256 threads = 4 waves; wave w owns 32x32 tile (nsub=(w>>1)*32, gsub=(w&1)*32).
// LDS tiles stored bf16 hi/lo with XOR swizzle byte^=(row&7)<<4 (G4).
// ---------------------------------------------------------------------------
__global__ __launch_bounds__(256) void gcn_kernel(
    const float* __restrict__ S, const float* __restrict__ adj,
    const float* __restrict__ w1g, const float* __restrict__ b1g,
    const float* __restrict__ W2, const float* __restrict__ b2g,
    float* __restrict__ outbuf)
{
    __shared__ __align__(16) short Ahi[64 * 64];   // adj[n][m]; reused as C_hi
    __shared__ __align__(16) short Alo[64 * 64];   //             reused as C_lo
    __shared__ __align__(16) short Bhi[64 * 64];   // h1T[g][m]
    __shared__ __align__(16) short Blo[64 * 64];
    __shared__ __align__(16) float srow[Nn];

    const int tid  = threadIdx.x;
    const int lane = tid & 63;
    const int w    = tid >> 6;         // 0..3
    const int l31  = lane & 31;
    const int lh   = lane >> 5;        // 0/1
    const int nb   = blockIdx.x * 64;
    const int bt   = blockIdx.y;
    const int nsub = (w >> 1) * 32, gsub = (w & 1) * 32;

    for (int i = tid; i < Nn; i += 256) srow[i] = S[(size_t)bt * Nn + i];

    // staging roles
    const int ar  = tid >> 2;            // adj row 0..63
    const int ac  = (tid & 3) * 16;      // adj col base
    const int hg  = tid & 63;            // h1T row (g)
    const int hms = (tid >> 6) * 16;     // h1T m-strip
    const float w1v = w1g[hg], b1v = b1g[hg];

    f32x16 acc;
#pragma unroll
    for (int r = 0; r < 16; ++r) acc[r] = 0.f;

    for (int mc = 0; mc < 8; ++mc) {
        __syncthreads();
        // ---- stage adj tile (hi/lo, swizzled) ----
        {
            const float* src = &adj[(size_t)(nb + ar) * Nn + mc * 64 + ac];
            float v[16];
            *(float4*)&v[0]  = *(const float4*)&src[0];
            *(float4*)&v[4]  = *(const float4*)&src[4];
            *(float4*)&v[8]  = *(const float4*)&src[8];
            *(float4*)&v[12] = *(const float4*)&src[12];
            bf16x8 h0, l0, h1, l1;
            split8(&v[0], h0, l0);
            split8(&v[8], h1, l1);
            unsigned base = (unsigned)(ar * 128 + ac * 2);
            unsigned swz  = ((unsigned)(ar & 7)) << 4;
            *(bf16x8*)((char*)Ahi + ((base +  0) ^ swz)) = h0;
            *(bf16x8*)((char*)Ahi + ((base + 16) ^ swz)) = h1;
            *(bf16x8*)((char*)Alo + ((base +  0) ^ swz)) = l0;
            *(bf16x8*)((char*)Alo + ((base + 16) ^ swz)) = l1;
        }
        // ---- stage h1T tile: h1[m][g] = relu(srow[m]*w1[g]+b1[g]) ----
        {
            float v[16];
#pragma unroll
            for (int q = 0; q < 16; q += 4) {
                float4 sv = *(float4*)&srow[mc * 64 + hms + q];
                v[q + 0] = fmaxf(sv.x * w1v + b1v, 0.f);
                v[q + 1] = fmaxf(sv.y * w1v + b1v, 0.f);
                v[q + 2] = fmaxf(sv.z * w1v + b1v, 0.f);
                v[q + 3] = fmaxf(sv.w * w1v + b1v, 0.f);
            }
            bf16x8 h0, l0, h1, l1;
            split8(&v[0], h0, l0);
            split8(&v[8], h1, l1);
            unsigned base = (unsigned)(hg * 128 + hms * 2);
            unsigned swz  = ((unsigned)(hg & 7)) << 4;
            *(bf16x8*)((char*)Bhi + ((base +  0) ^ swz)) = h0;
            *(bf16x8*)((char*)Bhi + ((base + 16) ^ swz)) = h1;
            *(bf16x8*)((char*)Blo + ((base +  0) ^ swz)) = l0;
            *(bf16x8*)((char*)Blo + ((base + 16) ^ swz)) = l1;
        }
        __syncthreads();
        // ---- fragments + 3-MFMA split accumulate ----
        const unsigned arow = (unsigned)(nsub + l31);
        const unsigned brow = (unsigned)(gsub + l31);
#pragma unroll
        for (int ks = 0; ks < 4; ++ks) {
            unsigned off  = (unsigned)(ks * 32 + lh * 16);
            unsigned aoff = arow * 128 + (off ^ ((arow & 7) << 4));
            unsigned boff = brow * 128 + (off ^ ((brow & 7) << 4));
            bf16x8 ah = *(bf16x8*)((char*)Ahi + aoff);
            bf16x8 al = *(bf16x8*)((char*)Alo + aoff);
            bf16x8 bh = *(bf16x8*)((char*)Bhi + boff);
            bf16x8 bl = *(bf16x8*)((char*)Blo + boff);
            acc = __builtin_amdgcn_mfma_f32_32x32x16_bf16(ah, bh, acc, 0, 0, 0);
            acc = __builtin_amdgcn_mfma_f32_32x32x16_bf16(ah, bl, acc, 0, 0, 0);
            acc = __builtin_amdgcn_mfma_f32_32x32x16_bf16(al, bh, acc, 0, 0, 0);
        }
    }

    // ---- write C (hi/lo bf16) into reused Ahi/Alo ----
    __syncthreads();
#pragma unroll
    for (int r = 0; r < 16; ++r) {
        int row = nsub + (r & 3) + 8 * (r >> 2) + 4 * lh;
        int col = gsub + l31;
        unsigned byte = ((unsigned)(row * 128 + col * 2)) ^ (((unsigned)(row & 7)) << 4);
        float v = acc[r];
        unsigned short ch = f2bf(v);
        *(unsigned short*)((char*)Ahi + byte) = ch;
        *(unsigned short*)((char*)Alo + byte) = f2bf(v - bf2f(ch));
    }
    __syncthreads();

    // ---- epilogue: out[n][h] = relu(b2 + C @ W2^T), W2 frags from global ----
    f32x16 acc2;
    {
        float b2v = b2g[gsub + l31];
#pragma unroll
        for (int r = 0; r < 16; ++r) acc2[r] = b2v;
    }
    const unsigned crow = (unsigned)(nsub + l31);
#pragma unroll
    for (int ks = 0; ks < 4; ++ks) {
        float v[8];
        const float* p = &W2[(size_t)(gsub + l31) * 64 + ks * 16 + lh * 8];
        *(float4*)&v[0] = *(const float4*)&p[0];
        *(float4*)&v[4] = *(const float4*)&p[4];
        bf16x8 w2h, w2l;
        split8(v, w2h, w2l);
        unsigned aoff = crow * 128 +
            (((unsigned)(ks * 32 + lh * 16)) ^ ((crow & 7) << 4));
        bf16x8 ch = *(bf16x8*)((char*)Ahi + aoff);
        bf16x8 cl = *(bf16x8*)((char*)Alo + aoff);
        acc2 = __builtin_amdgcn_mfma_f32_32x32x16_bf16(ch, w2h, acc2, 0, 0, 0);
        acc2 = __builtin_amdgcn_mfma_f32_32x32x16_bf16(ch, w2l, acc2, 0, 0, 0);
        acc2 = __builtin_amdgcn_mfma_f32_32x32x16_bf16(cl, w2h, acc2, 0, 0, 0);
    }
    const int b = bt >> 6, t = bt & 63;
#pragma unroll
    for (int r = 0; r < 16; ++r) {
        int n = nb + nsub + (r & 3) + 8 * (r >> 2) + 4 * lh;
        int h = gsub + l31;
        size_t m = (size_t)b * Nn + n;
        outbuf[(m * Tt + t) * LH + h] = fmaxf(acc2[r], 0.f);
    }
}

// ---------------------------------------------------------------------------
// LSTM layer: 32 seqs/block, 256 blocks (1/CU), 512 threads = 8 waves.
// Gate GEMM [32m x 256j x 64k(x) + 64k(h)] on mfma_f32_32x32x16_bf16,
// split-bf16. Weight B-frags preloaded to VGPRs (native Wih[j][k] layout is
// exactly the BT[col][k] the B fragment wants) -> zero weight LDS traffic.
// Wave w computes gate cols [w*32, w*32+32).
// ---------------------------------------------------------------------------
template <bool LAST>
__global__ __launch_bounds__(512, 1) void lstm_kernel(
    const float* __restrict__ xin, float* __restrict__ yout,
    const float* __restrict__ Wih, const float* __restrict__ Whh,
    const float* __restrict__ bih, const float* __restrict__ bhh,
    const float* __restrict__ fcW, const float* __restrict__ fcb,
    float* __restrict__ out)
{
    __shared__ __align__(16) short xhi[32 * 64], xlo[32 * 64];
    __shared__ __align__(16) short hhi[32 * 64], hlo[32 * 64];
    __shared__ __align__(16) float cst[32 * 64];
    __shared__ __align__(16) float gbuf[32 * 256];   // gates; reused as h_f32 for FC

    const int tid  = threadIdx.x;
    const int lane = tid & 63;
    const int w    = tid >> 6;        // wave 0..7
    const int l31  = lane & 31;
    const int lh   = lane >> 5;       // 0/1
    const int s0   = blockIdx.x * 32;
    const int jb   = w * 32;          // gate col base

    // ---- weight fragments (hi/lo) into registers, once ----
    bf16x8 wiH[4], wiL[4], whH[4], whL[4];
#pragma unroll
    for (int ks = 0; ks < 4; ++ks) {
        float v[8];
        const float* p = &Wih[(size_t)(jb + l31) * 64 + ks * 16 + lh * 8];
        *(float4*)&v[0] = *(const float4*)&p[0];
        *(float4*)&v[4] = *(const float4*)&p[4];
        split8(v, wiH[ks], wiL[ks]);
        const float* q = &Whh[(size_t)(jb + l31) * 64 + ks * 16 + lh * 8];
        *(float4*)&v[0] = *(const float4*)&q[0];
        *(float4*)&v[4] = *(const float4*)&q[4];
        split8(v, whH[ks], whL[ks]);
    }
    const float breg = bih[jb + l31] + bhh[jb + l31];

    for (int i = tid; i < 32 * 64; i += 512) { hhi[i] = 0; hlo[i] = 0; cst[i] = 0.f; }

    const int sm = tid >> 4;           // stage seq 0..31
    const int sc = (tid & 15) * 4;     // stage k col

    for (int t = 0; t < Tt; ++t) {
        // (1) stage x_t -> xhi/xlo (swizzled)
        {
            float4 xv = *(const float4*)&xin[((size_t)(s0 + sm) * Tt + t) * LH + sc];
            unsigned short a = f2bf(xv.x), b = f2bf(xv.y),
                           c = f2bf(xv.z), d = f2bf(xv.w);
            short4 hi4; hi4.x = (short)a; hi4.y = (short)b; hi4.z = (short)c; hi4.w = (short)d;
            short4 lo4;
            lo4.x = (short)f2bf(xv.x - bf2f(a)); lo4.y = (short)f2bf(xv.y - bf2f(b));
            lo4.z = (short)f2bf(xv.z - bf2f(c)); lo4.w = (short)f2bf(xv.w - bf2f(d));
            unsigned off = (unsigned)(sm * 128) +
                (((unsigned)(sc * 2)) ^ (((unsigned)(sm & 7)) << 4));
            *(short4*)((char*)xhi + off) = hi4;
            *(short4*)((char*)xlo + off) = lo4;
        }
        __syncthreads();   // (2) x staged; h,c from t-1 visible

        // (3) gate MFMAs
        f32x16 acc;
#pragma unroll
        for (int r = 0; r < 16; ++r) acc[r] = breg;
        const unsigned mrow = (unsigned)l31;
        const unsigned rbase = mrow * 128;
        const unsigned rswz  = (mrow & 7) << 4;
#pragma unroll
        for (int ks = 0; ks < 4; ++ks) {
            unsigned off = rbase + (((unsigned)(ks * 32 + lh * 16)) ^ rswz);
            bf16x8 xh = *(bf16x8*)((char*)xhi + off);
            bf16x8 xl = *(bf16x8*)((char*)xlo + off);
            acc = __builtin_amdgcn_mfma_f32_32x32x16_bf16(xh, wiH[ks], acc, 0, 0, 0);
            acc = __builtin_amdgcn_mfma_f32_32x32x16_bf16(xh, wiL[ks], acc, 0, 0, 0);
            acc = __builtin_amdgcn_mfma_f32_32x32x16_bf16(xl, wiH[ks], acc, 0, 0, 0);
            bf16x8 hh = *(bf16x8*)((char*)hhi + off);
            bf16x8 hl = *(bf16x8*)((char*)hlo + off);
            acc = __builtin_amdgcn_mfma_f32_32x32x16_bf16(hh, whH[ks], acc, 0, 0, 0);
            acc = __builtin_amdgcn_mfma_f32_32x32x16_bf16(hh, whL[ks], acc, 0, 0, 0);
            acc = __builtin_amdgcn_mfma_f32_32x32x16_bf16(hl, whH[ks], acc, 0, 0, 0);
        }
        // (4) scatter gate tile to gbuf
#pragma unroll
        for (int r = 0; r < 16; ++r) {
            int mr = (r & 3) + 8 * (r >> 2) + 4 * lh;
            gbuf[mr * 256 + jb + l31] = acc[r];
        }
        __syncthreads();   // (5)

        // (6) elementwise LSTM cell
        {
            const int m = tid >> 4;
            const int u = (tid & 15) * 4;
            f32x4 gi = *(f32x4*)&gbuf[m * 256 + u];
            f32x4 gf = *(f32x4*)&gbuf[m * 256 + 64 + u];
            f32x4 gg = *(f32x4*)&gbuf[m * 256 + 128 + u];
            f32x4 go = *(f32x4*)&gbuf[m * 256 + 192 + u];
            f32x4 cc = *(f32x4*)&cst[m * 64 + u];
            float hv[4];
            short4 hh4, hl4;
            short* hhp = (short*)&hh4; short* hlp = (short*)&hl4;
#pragma unroll
            for (int q = 0; q < 4; ++q) {
                float c  = sigf(gf[q]) * cc[q] + sigf(gi[q]) * tanhfast(gg[q]);
                float hv1 = sigf(go[q]) * tanhfast(c);
                cc[q] = c; hv[q] = hv1;
                unsigned short hb = f2bf(hv1);
                hhp[q] = (short)hb;
                hlp[q] = (short)f2bf(hv1 - bf2f(hb));
            }
            *(f32x4*)&cst[m * 64 + u] = cc;
            unsigned off = (unsigned)(m * 128) +
                (((unsigned)(u * 2)) ^ (((unsigned)(m & 7)) << 4));
            *(short4*)((char*)hhi + off) = hh4;
            *(short4*)((char*)hlo + off) = hl4;
            if constexpr (!LAST) {
                *(float4*)&yout[((size_t)(s0 + m) * Tt + t) * LH + u] =
                    make_float4(hv[0], hv[1], hv[2], hv[3]);
            } else if (t == Tt - 1) {
                // park final h (f32) over this thread's own i-gate cells
                gbuf[m * 256 + u + 0] = hv[0];
                gbuf[m * 256 + u + 1] = hv[1];
                gbuf[m * 256 + u + 2] = hv[2];
                gbuf[m * 256 + u + 3] = hv[3];
            }
        }
        // no barrier needed here: next iter's (2) orders (6) writes vs (3) reads
    }

    if constexpr (LAST) {
        __syncthreads();
        if (tid < 32) {
            float a = fcb[0];
#pragma unroll 8
            for (int k = 0; k < 64; ++k) a += gbuf[tid * 256 + k] * fcW[k];
            out[s0 + tid] = a;
        }
    }
}

// ---------------------------------------------------------------------------
extern "C" void kernel_launch(void* const* d_in, const int* in_sizes, int n_in,
                              void* d_out, int out_size, void* d_ws, size_t ws_size,
                              hipStream_t stream) {
    const float* X      = (const float*)d_in[0];
    const float* adj    = (const float*)d_in[1];
    const float* gcn1_W = (const float*)d_in[2];
    const float* gcn1_b = (const float*)d_in[3];
    const float* gcn2_W = (const float*)d_in[4];
    const float* gcn2_b = (const float*)d_in[5];
    const float* Wih0   = (const float*)d_in[6];
    const float* Whh0   = (const float*)d_in[7];
    const float* bih0   = (const float*)d_in[8];
    const float* bhh0   = (const float*)d_in[9];
    const float* Wih1   = (const float*)d_in[10];
    const float* Whh1   = (const float*)d_in[11];
    const float* bih1   = (const float*)d_in[12];
    const float* bhh1   = (const float*)d_in[13];
    const float* fc_W   = (const float*)d_in[14];
    const float* fc_b   = (const float*)d_in[15];

    float* S    = (float*)d_ws;                 // [1024][512]    2 MB
    float* buf0 = S + (size_t)BT * Nn;          // [8192][64][64] 134 MB

    // A: S = X * adj^T
    sgemm_kernel<<<dim3(Nn / 64, BT / 64), 256, 0, stream>>>(X, adj, S);
    // B: fused GCN -> buf0 in [m][t][h] seq layout
    gcn_kernel<<<dim3(Nn / 64, BT), 256, 0, stream>>>(
        S, adj, gcn1_W, gcn1_b, gcn2_W, gcn2_b, buf0);
    // C: LSTM layer 0, in-place on buf0
    lstm_kernel<false><<<Mseq / 32, 512, 0, stream>>>(
        buf0, buf0, Wih0, Whh0, bih0, bhh0, nullptr, nullptr, nullptr);
    // D: LSTM layer 1 + FC -> d_out
    lstm_kernel<true><<<Mseq / 32, 512, 0, stream>>>(
        buf0, nullptr, Wih1, Whh1, bih1, bhh1, fc_W, fc_b, (float*)d_out);
}

// Round 3
// 644.264 us; speedup vs baseline: 1.0091x; 1.0091x over previous
//
#include <hip/hip_runtime.h>
#include <hip/hip_bf16.h>

// Problem dims (fixed by setup_inputs)
#define Bb 16
#define Tt 64
#define Nn 512
#define BT (Bb*Tt)      // 1024
#define LH 64
#define Mseq (Bb*Nn)    // 8192

typedef short  bf16x8 __attribute__((ext_vector_type(8)));
typedef float  f32x16 __attribute__((ext_vector_type(16)));

__device__ __forceinline__ unsigned short f2bf(float f) {
    unsigned int u = __float_as_uint(f);
    return (unsigned short)((u + 0x7FFFu + ((u >> 16) & 1u)) >> 16);
}
__device__ __forceinline__ float bf2f(unsigned short b) {
    return __uint_as_float(((unsigned int)b) << 16);
}
__device__ __forceinline__ void split8(const float* v, bf16x8& hi, bf16x8& lo) {
#pragma unroll
    for (int i = 0; i < 8; ++i) {
        unsigned short h = f2bf(v[i]);
        hi[i] = (short)h;
        lo[i] = (short)f2bf(v[i] - bf2f(h));
    }
}
__device__ __forceinline__ float sigf(float x)  { return 1.f / (1.f + __expf(-x)); }
__device__ __forceinline__ float tanhfast(float x) { return 2.f / (1.f + __expf(-2.f * x)) - 1.f; }

// ---------------------------------------------------------------------------
// Kernel A: S[bt][n] = sum_m X[bt][m] * adj[n][m]   (fp32 VALU, small)
// ---------------------------------------------------------------------------
__global__ __launch_bounds__(256) void sgemm_kernel(
    const float* __restrict__ X, const float* __restrict__ adj,
    float* __restrict__ S)
{
    __shared__ __align__(16) float Xs[64 * 68];
    __shared__ __align__(16) float As[64 * 68];
    const int tid = threadIdx.x;
    const int nb  = blockIdx.x * 64;
    const int bt0 = blockIdx.y * 64;

    const int lr  = tid >> 4;
    const int lc4 = (tid & 15) * 4;
    const int r0  = 4 * (tid >> 4);
    const int c0  = 4 * (tid & 15);

    float acc[4][4] = {};

    for (int kc = 0; kc < 8; ++kc) {
        __syncthreads();
#pragma unroll
        for (int s = 0; s < 64; s += 16) {
            *(float4*)&Xs[(lr + s) * 68 + lc4] =
                *(const float4*)&X[(size_t)(bt0 + lr + s) * Nn + kc * 64 + lc4];
            *(float4*)&As[(lr + s) * 68 + lc4] =
                *(const float4*)&adj[(size_t)(nb + lr + s) * Nn + kc * 64 + lc4];
        }
        __syncthreads();
#pragma unroll 4
        for (int k4 = 0; k4 < 64; k4 += 4) {
            float4 x4[4], a4[4];
#pragma unroll
            for (int i = 0; i < 4; ++i) x4[i] = *(float4*)&Xs[(r0 + i) * 68 + k4];
#pragma unroll
            for (int j = 0; j < 4; ++j) a4[j] = *(float4*)&As[(c0 + j) * 68 + k4];
#pragma unroll
            for (int i = 0; i < 4; ++i)
#pragma unroll
                for (int j = 0; j < 4; ++j)
                    acc[i][j] += x4[i].x * a4[j].x + x4[i].y * a4[j].y +
                                 x4[i].z * a4[j].z + x4[i].w * a4[j].w;
        }
    }
#pragma unroll
    for (int i = 0; i < 4; ++i) {
        float4 v = make_float4(acc[i][0], acc[i][1], acc[i][2], acc[i][3]);
        *(float4*)&S[(size_t)(bt0 + r0 + i) * Nn + nb + c0] = v;
    }
}

// ---------------------------------------------------------------------------
// Kernel P: pack adj into MFMA A-fragment-major bf16 hi/lo, with the m-slot
// permutation sigma matching the z-store layout:
//   slot (ks,kk) -> m_local = (ks>>1)*32 + (kk&3) + 8*(kk>>2) + 4*(ks&1)
// Layout: [nt8][mc8][sub2][ks4][lane64][8 bf16]  (hi and lo arrays)
// ---------------------------------------------------------------------------
__global__ __launch_bounds__(256) void adjpack_kernel(
    const float* __restrict__ adj, short* __restrict__ Phi, short* __restrict__ Plo)
{
    const int id   = blockIdx.x * 256 + threadIdx.x;   // 0..32767
    const int lane = id & 63;
    const int ks   = (id >> 6) & 3;
    const int sub  = (id >> 8) & 1;
    const int mc   = (id >> 9) & 7;
    const int nt   = (id >> 12) & 7;
    const int row  = nt * 64 + sub * 32 + (lane & 31);

    float v[8];
#pragma unroll
    for (int e = 0; e < 8; ++e) {
        int kk = ((lane >> 5) << 3) + e;
        int ml = ((ks >> 1) << 5) + (kk & 3) + ((kk >> 2) << 3) + ((ks & 1) << 2);
        v[e] = adj[(size_t)row * Nn + mc * 64 + ml];
    }
    bf16x8 hi, lo;
    split8(v, hi, lo);
    *(bf16x8*)&Phi[(size_t)id * 8] = hi;
    *(bf16x8*)&Plo[(size_t)id * 8] = lo;
}

// ---------------------------------------------------------------------------
// Kernel G: fused GCN (z-form).
//   z[m][h] = sum_g relu(S[bt][m]*w1[g]+b1[g]) * W2[h][g]   (phase 1, MFMA,
//             h1 fragments built per-lane in registers, z -> LDS frag-major)
//   out[n][h] = relu(b2[h] + sum_m adj[n][m] * z[m][h])     (phase 2, MFMA,
//             adj fragments direct per-lane global loads from adjP)
// Block = (bt, h-half 32). 256 threads = 4 waves.
// Output packed u32 (bf16hi<<16 | bf16lo) in LSTM layout [m][t][h].
// ---------------------------------------------------------------------------
__global__ __launch_bounds__(256) void gcnz_kernel(
    const float* __restrict__ S,
    const short* __restrict__ Phi, const short* __restrict__ Plo,
    const float* __restrict__ w1g, const float* __restrict__ b1g,
    const float* __restrict__ W2, const float* __restrict__ b2g,
    unsigned* __restrict__ outbuf)
{
    __shared__ __align__(16) short zhi[16384];   // 32 frags x 1024B
    __shared__ __align__(16) short zlo[16384];

    const int tid = threadIdx.x;
    const int l   = tid & 63;
    const int w   = tid >> 6;
    const int l31 = l & 31;
    const int lh  = l >> 5;
    const int bt  = blockIdx.x >> 1;
    const int hh  = blockIdx.x & 1;

    // W2 B-fragments (lane: col h = hh*32+l31, k-octet g) — native rows
    bf16x8 w2H[4], w2L[4];
#pragma unroll
    for (int ks = 0; ks < 4; ++ks) {
        int g0 = ks * 16 + lh * 8;
        float v[8];
        *(float4*)&v[0] = *(const float4*)&W2[(size_t)(hh * 32 + l31) * 64 + g0];
        *(float4*)&v[4] = *(const float4*)&W2[(size_t)(hh * 32 + l31) * 64 + g0 + 4];
        split8(v, w2H[ks], w2L[ks]);
    }

    // ---- phase 1: z tiles ----
#pragma unroll
    for (int mcp = 0; mcp < 2; ++mcp) {
        const int mc = w * 2 + mcp;
#pragma unroll
        for (int msub = 0; msub < 2; ++msub) {
            float s = S[(size_t)bt * Nn + mc * 64 + msub * 32 + l31];
            f32x16 a;
#pragma unroll
            for (int r = 0; r < 16; ++r) a[r] = 0.f;
#pragma unroll
            for (int ks = 0; ks < 4; ++ks) {
                int g0 = ks * 16 + lh * 8;
                float4 wa = *(const float4*)&w1g[g0];
                float4 wb = *(const float4*)&w1g[g0 + 4];
                float4 ba = *(const float4*)&b1g[g0];
                float4 bb = *(const float4*)&b1g[g0 + 4];
                float hv[8];
                hv[0] = fmaxf(s * wa.x + ba.x, 0.f); hv[1] = fmaxf(s * wa.y + ba.y, 0.f);
                hv[2] = fmaxf(s * wa.z + ba.z, 0.f); hv[3] = fmaxf(s * wa.w + ba.w, 0.f);
                hv[4] = fmaxf(s * wb.x + bb.x, 0.f); hv[5] = fmaxf(s * wb.y + bb.y, 0.f);
                hv[6] = fmaxf(s * wb.z + bb.z, 0.f); hv[7] = fmaxf(s * wb.w + bb.w, 0.f);
                bf16x8 h1h, h1l;
                split8(hv, h1h, h1l);
                a = __builtin_amdgcn_mfma_f32_32x32x16_bf16(h1h, w2H[ks], a, 0, 0, 0);
                a = __builtin_amdgcn_mfma_f32_32x32x16_bf16(h1h, w2L[ks], a, 0, 0, 0);
                a = __builtin_amdgcn_mfma_f32_32x32x16_bf16(h1l, w2H[ks], a, 0, 0, 0);
            }
            // store z frags (hi/lo), contiguous b128 per lane
            const int ks_st = msub * 2 + lh;
#pragma unroll
            for (int half = 0; half < 2; ++half) {
                bf16x8 sh, sl;
#pragma unroll
                for (int e = 0; e < 8; ++e) {
                    float v = a[half * 8 + e];
                    unsigned short h = f2bf(v);
                    sh[e] = (short)h;
                    sl[e] = (short)f2bf(v - bf2f(h));
                }
                unsigned off = (unsigned)((mc * 4 + ks_st) * 1024 + (half * 32 + l31) * 16);
                *(bf16x8*)((char*)zhi + off) = sh;
                *(bf16x8*)((char*)zlo + off) = sl;
            }
        }
    }
    __syncthreads();

    // ---- phase 2: out = relu(b2 + adj @ z) ----
    const int b = bt >> 6, t = bt & 63;
    const float b2v = b2g[hh * 32 + l31];
#pragma unroll
    for (int nt2 = 0; nt2 < 2; ++nt2) {
        const int nt = w * 2 + nt2;
#pragma unroll
        for (int nsub = 0; nsub < 2; ++nsub) {
            f32x16 a;
#pragma unroll
            for (int r = 0; r < 16; ++r) a[r] = b2v;
            for (int mc = 0; mc < 8; ++mc) {
#pragma unroll
                for (int ks = 0; ks < 4; ++ks) {
                    size_t fo = ((((size_t)(nt * 8 + mc) * 2 + nsub) * 4 + ks) * 64 + l) * 8;
                    bf16x8 ah = *(const bf16x8*)&Phi[fo];
                    bf16x8 al = *(const bf16x8*)&Plo[fo];
                    unsigned zo = (unsigned)((mc * 4 + ks) * 1024 + l * 16);
                    bf16x8 bh = *(bf16x8*)((char*)zhi + zo);
                    bf16x8 bl = *(bf16x8*)((char*)zlo + zo);
                    a = __builtin_amdgcn_mfma_f32_32x32x16_bf16(ah, bh, a, 0, 0, 0);
                    a = __builtin_amdgcn_mfma_f32_32x32x16_bf16(ah, bl, a, 0, 0, 0);
                    a = __builtin_amdgcn_mfma_f32_32x32x16_bf16(al, bh, a, 0, 0, 0);
                }
            }
            const int h = hh * 32 + l31;
#pragma unroll
            for (int r = 0; r < 16; ++r) {
                int n = nt * 64 + nsub * 32 + (r & 3) + 8 * (r >> 2) + 4 * lh;
                float v = fmaxf(a[r], 0.f);
                unsigned short hb = f2bf(v);
                unsigned short lb = f2bf(v - bf2f(hb));
                outbuf[((size_t)(b * Nn + n) * Tt + t) * 64 + h] =
                    ((unsigned)hb << 16) | (unsigned)lb;
            }
        }
    }
}

// ---------------------------------------------------------------------------
// Kernel L: LSTM layer. 32 seqs/block, 256 blocks (1/CU), 512 threads = 8 waves.
// MFMA orientation C[j][m] = W[j][k] @ x[k][m]: weights (A) in registers,
// x/h (B) fragment-major in LDS. Per-wave gate-column remap
//   j-local c -> j_global = (c>>3)*64 + w*8 + (c&7)
// makes acc[r] hold gate (r>>2) of unit w*8+4*lh1+(r&3) for seq m=l31:
// the whole LSTM cell is per-lane in registers (no LDS gate transpose).
// x input / y output are packed u32 (bf16hi<<16|bf16lo).
// ---------------------------------------------------------------------------
#define FRS 1072   // frag stride bytes (1024 + 48 pad, 16B aligned, odd granule)
template <bool LAST>
__global__ __launch_bounds__(512) void lstm_kernel(
    const unsigned* __restrict__ xin, unsigned* __restrict__ yout,
    const float* __restrict__ Wih, const float* __restrict__ Whh,
    const float* __restrict__ bih, const float* __restrict__ bhh,
    const float* __restrict__ fcW, const float* __restrict__ fcb,
    float* __restrict__ out)
{
    __shared__ __align__(16) char xh_[4 * FRS];
    __shared__ __align__(16) char xl_[4 * FRS];
    __shared__ __align__(16) char hh_[4 * FRS];
    __shared__ __align__(16) char hl_[4 * FRS];
    __shared__ float fcp[32 * 17];

    const int tid = threadIdx.x;
    const int l   = tid & 63;
    const int w   = tid >> 6;
    const int l31 = l & 31;
    const int lh1 = l >> 5;
    const int s0  = blockIdx.x * 32;

    // weight A-fragments (hi/lo) once; row j via gate/unit remap
    bf16x8 wiH[4], wiL[4], whH[4], whL[4];
    {
        const int jg = ((l31 >> 3) << 6) + w * 8 + (l31 & 7);
#pragma unroll
        for (int ks = 0; ks < 4; ++ks) {
            int k0 = ks * 16 + lh1 * 8;
            float v[8];
            *(float4*)&v[0] = *(const float4*)&Wih[(size_t)jg * 64 + k0];
            *(float4*)&v[4] = *(const float4*)&Wih[(size_t)jg * 64 + k0 + 4];
            split8(v, wiH[ks], wiL[ks]);
            *(float4*)&v[0] = *(const float4*)&Whh[(size_t)jg * 64 + k0];
            *(float4*)&v[4] = *(const float4*)&Whh[(size_t)jg * 64 + k0 + 4];
            split8(v, whH[ks], whL[ks]);
        }
    }
    float bias_r[16];
#pragma unroll
    for (int r = 0; r < 16; ++r) {
        int j = ((r >> 2) << 6) + w * 8 + (r & 3) + 4 * lh1;
        bias_r[r] = bih[j] + bhh[j];
    }
    float fw[4];
    if constexpr (LAST) {
#pragma unroll
        for (int i = 0; i < 4; ++i) fw[i] = fcW[w * 8 + 4 * lh1 + i];
    }

    // zero h frags (h0 = 0; bf16 zero = 0x0000)
    for (int i = tid; i < 4 * FRS / 4; i += 512) {
        ((int*)hh_)[i] = 0;
        ((int*)hl_)[i] = 0;
    }

    // staging role: 4 k-elems per thread
    const int sm = tid >> 4;
    const int sk = (tid & 15) * 4;
    const unsigned stb = (unsigned)((sk >> 4) * FRS + ((((sk >> 3) & 1) << 5) + sm) * 16 + (sk & 7) * 2);
    const unsigned hwb = (unsigned)((w >> 1) * FRS + (((w & 1) << 5) + l31) * 16 + lh1 * 8);

    float cst[4] = {0.f, 0.f, 0.f, 0.f};
    short4 hph = {0, 0, 0, 0}, hpl = {0, 0, 0, 0};
    float hfin[4];

    uint4 xp = *(const uint4*)&xin[((size_t)(s0 + sm) * Tt + 0) * 64 + sk];

    for (int t = 0; t < Tt; ++t) {
        // (A) write x(t) and h(t-1) frags
        short4 sh, sl;
        sh.x = (short)(xp.x >> 16); sl.x = (short)(xp.x & 0xffff);
        sh.y = (short)(xp.y >> 16); sl.y = (short)(xp.y & 0xffff);
        sh.z = (short)(xp.z >> 16); sl.z = (short)(xp.z & 0xffff);
        sh.w = (short)(xp.w >> 16); sl.w = (short)(xp.w & 0xffff);
        *(short4*)(xh_ + stb) = sh;
        *(short4*)(xl_ + stb) = sl;
        if (t > 0) {
            *(short4*)(hh_ + hwb) = hph;
            *(short4*)(hl_ + hwb) = hpl;
        }
        // (B) prefetch x(t+1)
        {
            int tn = (t < Tt - 1) ? t + 1 : t;
            xp = *(const uint4*)&xin[((size_t)(s0 + sm) * Tt + tn) * 64 + sk];
        }
        __syncthreads();

        // (C) gates: two independent MFMA chains (x-part, h-part)
        f32x16 a1, a2;
#pragma unroll
        for (int r = 0; r < 16; ++r) { a1[r] = 0.f; a2[r] = 0.f; }
#pragma unroll
        for (int ks = 0; ks < 4; ++ks) {
            bf16x8 xh = *(bf16x8*)(xh_ + ks * FRS + l * 16);
            bf16x8 xl = *(bf16x8*)(xl_ + ks * FRS + l * 16);
            a1 = __builtin_amdgcn_mfma_f32_32x32x16_bf16(wiH[ks], xh, a1, 0, 0, 0);
            a1 = __builtin_amdgcn_mfma_f32_32x32x16_bf16(wiL[ks], xh, a1, 0, 0, 0);
            a1 = __builtin_amdgcn_mfma_f32_32x32x16_bf16(wiH[ks], xl, a1, 0, 0, 0);
            bf16x8 hh = *(bf16x8*)(hh_ + ks * FRS + l * 16);
            bf16x8 hl = *(bf16x8*)(hl_ + ks * FRS + l * 16);
            a2 = __builtin_amdgcn_mfma_f32_32x32x16_bf16(whH[ks], hh, a2, 0, 0, 0);
            a2 = __builtin_amdgcn_mfma_f32_32x32x16_bf16(whL[ks], hh, a2, 0, 0, 0);
            a2 = __builtin_amdgcn_mfma_f32_32x32x16_bf16(whH[ks], hl, a2, 0, 0, 0);
        }

        // (D) cell, fully in-lane: seq m = l31, units w*8 + 4*lh1 + {0..3}
        unsigned yq[4];
#pragma unroll
        for (int ui = 0; ui < 4; ++ui) {
            float gi = a1[ui]      + a2[ui]      + bias_r[ui];
            float gf = a1[4 + ui]  + a2[4 + ui]  + bias_r[4 + ui];
            float gg = a1[8 + ui]  + a2[8 + ui]  + bias_r[8 + ui];
            float go = a1[12 + ui] + a2[12 + ui] + bias_r[12 + ui];
            float c  = sigf(gf) * cst[ui] + sigf(gi) * tanhfast(gg);
            float hv = sigf(go) * tanhfast(c);
            cst[ui] = c;
            unsigned short hb = f2bf(hv);
            unsigned short lb = f2bf(hv - bf2f(hb));
            ((short*)&hph)[ui] = (short)hb;
            ((short*)&hpl)[ui] = (short)lb;
            if constexpr (!LAST) {
                yq[ui] = ((unsigned)hb << 16) | (unsigned)lb;
            } else {
                if (t == Tt - 1) hfin[ui] = hv;
            }
        }
        if constexpr (!LAST) {
            *(uint4*)&yout[((size_t)(s0 + l31) * Tt + t) * 64 + w * 8 + 4 * lh1] =
                make_uint4(yq[0], yq[1], yq[2], yq[3]);
        }
        __syncthreads();
    }

    if constexpr (LAST) {
        float part = hfin[0] * fw[0] + hfin[1] * fw[1] + hfin[2] * fw[2] + hfin[3] * fw[3];
        fcp[l31 * 17 + w * 2 + lh1] = part;
        __syncthreads();
        if (tid < 32) {
            float s = fcb[0];
#pragma unroll
            for (int i = 0; i < 16; ++i) s += fcp[tid * 17 + i];
            out[s0 + tid] = s;
        }
    }
}

// ---------------------------------------------------------------------------
extern "C" void kernel_launch(void* const* d_in, const int* in_sizes, int n_in,
                              void* d_out, int out_size, void* d_ws, size_t ws_size,
                              hipStream_t stream) {
    const float* X      = (const float*)d_in[0];
    const float* adj    = (const float*)d_in[1];
    const float* gcn1_W = (const float*)d_in[2];
    const float* gcn1_b = (const float*)d_in[3];
    const float* gcn2_W = (const float*)d_in[4];
    const float* gcn2_b = (const float*)d_in[5];
    const float* Wih0   = (const float*)d_in[6];
    const float* Whh0   = (const float*)d_in[7];
    const float* bih0   = (const float*)d_in[8];
    const float* bhh0   = (const float*)d_in[9];
    const float* Wih1   = (const float*)d_in[10];
    const float* Whh1   = (const float*)d_in[11];
    const float* bih1   = (const float*)d_in[12];
    const float* bhh1   = (const float*)d_in[13];
    const float* fc_W   = (const float*)d_in[14];
    const float* fc_b   = (const float*)d_in[15];

    char* base = (char*)d_ws;
    float*    S      = (float*)base;                                   // 2 MB
    unsigned* buf0   = (unsigned*)(base + (size_t)BT * Nn * 4);        // 134 MB packed
    short*    adjPhi = (short*)(base + (size_t)BT * Nn * 4 + (size_t)Mseq * Tt * LH * 4);
    short*    adjPlo = adjPhi + 32768 * 8;                             // 512 KB each

    // A: S = X * adj^T  (fp32)
    sgemm_kernel<<<dim3(Nn / 64, BT / 64), 256, 0, stream>>>(X, adj, S);
    // P: adj -> fragment-major bf16 hi/lo
    adjpack_kernel<<<128, 256, 0, stream>>>(adj, adjPhi, adjPlo);
    // G: fused GCN -> buf0 (packed bf16 pairs, [m][t][h])
    gcnz_kernel<<<2048, 256, 0, stream>>>(
        S, adjPhi, adjPlo, gcn1_W, gcn1_b, gcn2_W, gcn2_b, buf0);
    // L0: LSTM layer 0, in-place on buf0
    lstm_kernel<false><<<Mseq / 32, 512, 0, stream>>>(
        buf0, buf0, Wih0, Whh0, bih0, bhh0, nullptr, nullptr, nullptr);
    // L1: LSTM layer 1 + FC -> d_out
    lstm_kernel<true><<<Mseq / 32, 512, 0, stream>>>(
        buf0, nullptr, Wih1, Whh1, bih1, bhh1, fc_W, fc_b, (float*)d_out);
}

// Round 4
// 640.389 us; speedup vs baseline: 1.0152x; 1.0061x over previous
//
#include <hip/hip_runtime.h>
#include <hip/hip_bf16.h>

// Problem dims (fixed by setup_inputs)
#define Bb 16
#define Tt 64
#define Nn 512
#define BT (Bb*Tt)      // 1024
#define LH 64
#define Mseq (Bb*Nn)    // 8192

typedef short  bf16x8 __attribute__((ext_vector_type(8)));
typedef float  f32x16 __attribute__((ext_vector_type(16)));

__device__ __forceinline__ unsigned short f2bf(float f) {
    unsigned int u = __float_as_uint(f);
    return (unsigned short)((u + 0x7FFFu + ((u >> 16) & 1u)) >> 16);
}
__device__ __forceinline__ float bf2f(unsigned short b) {
    return __uint_as_float(((unsigned int)b) << 16);
}
__device__ __forceinline__ void split8(const float* v, bf16x8& hi, bf16x8& lo) {
#pragma unroll
    for (int i = 0; i < 8; ++i) {
        unsigned short h = f2bf(v[i]);
        hi[i] = (short)h;
        lo[i] = (short)f2bf(v[i] - bf2f(h));
    }
}
__device__ __forceinline__ float sigf(float x)  { return 1.f / (1.f + __expf(-x)); }
__device__ __forceinline__ float tanhfast(float x) { return 2.f / (1.f + __expf(-2.f * x)) - 1.f; }

// ---------------------------------------------------------------------------
// Kernel A: S[bt][n] = sum_m X[bt][m] * adj[n][m]   (fp32 VALU, small)
// ---------------------------------------------------------------------------
__global__ __launch_bounds__(256) void sgemm_kernel(
    const float* __restrict__ X, const float* __restrict__ adj,
    float* __restrict__ S)
{
    __shared__ __align__(16) float Xs[64 * 68];
    __shared__ __align__(16) float As[64 * 68];
    const int tid = threadIdx.x;
    const int nb  = blockIdx.x * 64;
    const int bt0 = blockIdx.y * 64;

    const int lr  = tid >> 4;
    const int lc4 = (tid & 15) * 4;
    const int r0  = 4 * (tid >> 4);
    const int c0  = 4 * (tid & 15);

    float acc[4][4] = {};

    for (int kc = 0; kc < 8; ++kc) {
        __syncthreads();
#pragma unroll
        for (int s = 0; s < 64; s += 16) {
            *(float4*)&Xs[(lr + s) * 68 + lc4] =
                *(const float4*)&X[(size_t)(bt0 + lr + s) * Nn + kc * 64 + lc4];
            *(float4*)&As[(lr + s) * 68 + lc4] =
                *(const float4*)&adj[(size_t)(nb + lr + s) * Nn + kc * 64 + lc4];
        }
        __syncthreads();
#pragma unroll 4
        for (int k4 = 0; k4 < 64; k4 += 4) {
            float4 x4[4], a4[4];
#pragma unroll
            for (int i = 0; i < 4; ++i) x4[i] = *(float4*)&Xs[(r0 + i) * 68 + k4];
#pragma unroll
            for (int j = 0; j < 4; ++j) a4[j] = *(float4*)&As[(c0 + j) * 68 + k4];
#pragma unroll
            for (int i = 0; i < 4; ++i)
#pragma unroll
                for (int j = 0; j < 4; ++j)
                    acc[i][j] += x4[i].x * a4[j].x + x4[i].y * a4[j].y +
                                 x4[i].z * a4[j].z + x4[i].w * a4[j].w;
        }
    }
#pragma unroll
    for (int i = 0; i < 4; ++i) {
        float4 v = make_float4(acc[i][0], acc[i][1], acc[i][2], acc[i][3]);
        *(float4*)&S[(size_t)(bt0 + r0 + i) * Nn + nb + c0] = v;
    }
}

// ---------------------------------------------------------------------------
// Kernel P: pack adj -> A-fragment-major bf16 hi/lo with m-permutation PI
// baked in so that the gcnz z-accumulator register layout IS the B-frag:
//   PI(k) = ks*16 + lh*4 + (e&3) + 8*(e>>2)   for k = ks*16 + lh*8 + e
// Layout: flat g = (((nt*16 + ms)*2 + ns)*2 + ks)*64 + lane ; elem e:
//   adj[nt*64 + ns*32 + (lane&31)][ms*32 + PI(ks,lane>>5,e)]
// ---------------------------------------------------------------------------
__global__ __launch_bounds__(256) void adjpack_kernel(
    const float* __restrict__ adj, short* __restrict__ Phi, short* __restrict__ Plo)
{
    const int g    = blockIdx.x * 256 + threadIdx.x;   // 0..32767
    const int lane = g & 63;
    const int ks   = (g >> 6) & 1;
    const int ns   = (g >> 7) & 1;
    const int ms   = (g >> 8) & 15;
    const int nt   = (g >> 12) & 7;
    const int n    = nt * 64 + ns * 32 + (lane & 31);
    const int lh   = lane >> 5;

    float v[8];
#pragma unroll
    for (int e = 0; e < 8; ++e) {
        int pi = ks * 16 + lh * 4 + (e & 3) + 8 * (e >> 2);
        v[e] = adj[(size_t)n * Nn + ms * 32 + pi];
    }
    bf16x8 hi, lo;
    split8(v, hi, lo);
    *(bf16x8*)&Phi[(size_t)g * 8] = hi;
    *(bf16x8*)&Plo[(size_t)g * 8] = lo;
}

// ---------------------------------------------------------------------------
// Kernel G: fused GCN, register-only z.
// Block = (btg of 4 bt) x (nt of 64 n). 4 waves; wave w owns bt = btg*4+w.
// Per (mc, msub): z C-tiles (hh0/hh1, 2 chains) -> split to bf16 B-frags
// (register layout == B-frag under PI) -> bmm MFMAs into 4 persistent accs.
// No LDS at all; adjP/W2/w1/b1 reads are L1/L2-resident.
// ---------------------------------------------------------------------------
__device__ __forceinline__ void bmm_step(
    const f32x16& az, const short* __restrict__ Phi, const short* __restrict__ Plo,
    size_t abase, int l, f32x16& acc_ns0, f32x16& acc_ns1)
{
    // build z B-frags from accumulator registers (layout matches via PI)
    bf16x8 zH[2], zL[2];
#pragma unroll
    for (int kb = 0; kb < 2; ++kb) {
#pragma unroll
        for (int e = 0; e < 8; ++e) {
            float v = az[kb * 8 + e];
            unsigned short hb = f2bf(v);
            zH[kb][e] = (short)hb;
            zL[kb][e] = (short)f2bf(v - bf2f(hb));
        }
    }
#pragma unroll
    for (int ns = 0; ns < 2; ++ns) {
#pragma unroll
        for (int kb = 0; kb < 2; ++kb) {
            size_t fo = abase + (size_t)((ns * 2 + kb) * 64 + l) * 8;
            bf16x8 ah = *(const bf16x8*)&Phi[fo];
            bf16x8 al = *(const bf16x8*)&Plo[fo];
            if (ns == 0) {
                acc_ns0 = __builtin_amdgcn_mfma_f32_32x32x16_bf16(ah, zH[kb], acc_ns0, 0, 0, 0);
                acc_ns0 = __builtin_amdgcn_mfma_f32_32x32x16_bf16(ah, zL[kb], acc_ns0, 0, 0, 0);
                acc_ns0 = __builtin_amdgcn_mfma_f32_32x32x16_bf16(al, zH[kb], acc_ns0, 0, 0, 0);
            } else {
                acc_ns1 = __builtin_amdgcn_mfma_f32_32x32x16_bf16(ah, zH[kb], acc_ns1, 0, 0, 0);
                acc_ns1 = __builtin_amdgcn_mfma_f32_32x32x16_bf16(ah, zL[kb], acc_ns1, 0, 0, 0);
                acc_ns1 = __builtin_amdgcn_mfma_f32_32x32x16_bf16(al, zH[kb], acc_ns1, 0, 0, 0);
            }
        }
    }
}

__global__ __launch_bounds__(256, 2) void gcnz_kernel(
    const float* __restrict__ S,
    const short* __restrict__ Phi, const short* __restrict__ Plo,
    const float* __restrict__ w1g, const float* __restrict__ b1g,
    const float* __restrict__ W2, const float* __restrict__ b2g,
    unsigned* __restrict__ outbuf)
{
    const int tid = threadIdx.x;
    const int l   = tid & 63;
    const int w   = tid >> 6;
    const int l31 = l & 31;
    const int lh  = l >> 5;
    const int btg = blockIdx.x >> 3;
    const int nt  = blockIdx.x & 7;
    const int bt  = btg * 4 + w;

    // hoisted W2 B-frags: col h = hh*32+l31, k octet g = kg*16+lh*8+e
    bf16x8 w2H[2][4], w2L[2][4];
#pragma unroll
    for (int hh = 0; hh < 2; ++hh)
#pragma unroll
        for (int kg = 0; kg < 4; ++kg) {
            float v[8];
            const float* p = &W2[(size_t)(hh * 32 + l31) * 64 + kg * 16 + lh * 8];
            *(float4*)&v[0] = *(const float4*)&p[0];
            *(float4*)&v[4] = *(const float4*)&p[4];
            split8(v, w2H[hh][kg], w2L[hh][kg]);
        }

    f32x16 o00, o01, o10, o11;   // [ns][hh]
    {
        float b20 = b2g[l31], b21 = b2g[32 + l31];
#pragma unroll
        for (int r = 0; r < 16; ++r) { o00[r] = b20; o01[r] = b21; o10[r] = b20; o11[r] = b21; }
    }

    const float* Srow = &S[(size_t)bt * Nn];

    for (int mc = 0; mc < 8; ++mc) {
#pragma unroll
        for (int ms = 0; ms < 2; ++ms) {
            const float sv = Srow[mc * 64 + ms * 32 + l31];
            // z chains (hh0, hh1)
            f32x16 az0, az1;
#pragma unroll
            for (int r = 0; r < 16; ++r) { az0[r] = 0.f; az1[r] = 0.f; }
#pragma unroll
            for (int kg = 0; kg < 4; ++kg) {
                int g0 = kg * 16 + lh * 8;
                float4 wa = *(const float4*)&w1g[g0];
                float4 wb = *(const float4*)&w1g[g0 + 4];
                float4 ba = *(const float4*)&b1g[g0];
                float4 bb = *(const float4*)&b1g[g0 + 4];
                float hv[8];
                hv[0] = fmaxf(sv * wa.x + ba.x, 0.f); hv[1] = fmaxf(sv * wa.y + ba.y, 0.f);
                hv[2] = fmaxf(sv * wa.z + ba.z, 0.f); hv[3] = fmaxf(sv * wa.w + ba.w, 0.f);
                hv[4] = fmaxf(sv * wb.x + bb.x, 0.f); hv[5] = fmaxf(sv * wb.y + bb.y, 0.f);
                hv[6] = fmaxf(sv * wb.z + bb.z, 0.f); hv[7] = fmaxf(sv * wb.w + bb.w, 0.f);
                bf16x8 h1h, h1l;
                split8(hv, h1h, h1l);
                az0 = __builtin_amdgcn_mfma_f32_32x32x16_bf16(h1h, w2H[0][kg], az0, 0, 0, 0);
                az0 = __builtin_amdgcn_mfma_f32_32x32x16_bf16(h1h, w2L[0][kg], az0, 0, 0, 0);
                az0 = __builtin_amdgcn_mfma_f32_32x32x16_bf16(h1l, w2H[0][kg], az0, 0, 0, 0);
                az1 = __builtin_amdgcn_mfma_f32_32x32x16_bf16(h1h, w2H[1][kg], az1, 0, 0, 0);
                az1 = __builtin_amdgcn_mfma_f32_32x32x16_bf16(h1h, w2L[1][kg], az1, 0, 0, 0);
                az1 = __builtin_amdgcn_mfma_f32_32x32x16_bf16(h1l, w2H[1][kg], az1, 0, 0, 0);
            }
            // bmm: accO[ns][hh] += adjfrag(ns, ms_global, kb) * zfrag(kb)
            const size_t abase = (size_t)(nt * 16 + mc * 2 + ms) * 2048;
            bmm_step(az0, Phi, Plo, abase, l, o00, o10);
            bmm_step(az1, Phi, Plo, abase, l, o01, o11);
        }
    }

    // epilogue: relu + pack u32 (hi|lo) -> buf0 [m=b*512+n][t][h]
    const int b = bt >> 6, t = bt & 63;
#define STORE_ACC(ACC, NS, HH)                                                  \
    {                                                                           \
        _Pragma("unroll")                                                       \
        for (int r = 0; r < 16; ++r) {                                          \
            int n = nt * 64 + (NS) * 32 + (r & 3) + 8 * (r >> 2) + 4 * lh;      \
            int h = (HH) * 32 + l31;                                            \
            float v = fmaxf(ACC[r], 0.f);                                       \
            unsigned short hb = f2bf(v);                                        \
            unsigned short lb = f2bf(v - bf2f(hb));                             \
            outbuf[((size_t)(b * Nn + n) * Tt + t) * 64 + h] =                  \
                ((unsigned)hb << 16) | (unsigned)lb;                            \
        }                                                                       \
    }
    STORE_ACC(o00, 0, 0)
    STORE_ACC(o01, 0, 1)
    STORE_ACC(o10, 1, 0)
    STORE_ACC(o11, 1, 1)
#undef STORE_ACC
}

// ---------------------------------------------------------------------------
// Kernel L: LSTM layer. 32 seqs/block, 256 blocks (1/CU), 512 threads = 8 waves.
// MFMA C[j][m] = W[j][k] @ x[k][m]; weights in registers; x/h frag-major LDS.
// v2: x(t+1) prefetch issued BEFORE the MFMA chain (drained by the post-cell
// barrier ~1500cyc later, not immediately); 4 independent MFMA chains.
// ---------------------------------------------------------------------------
#define FRS 1072   // frag stride bytes (1024 + 48 pad)

__device__ __forceinline__ void stage_x(uint4 xp, unsigned stb, char* xh_, char* xl_) {
    short4 sh, sl;
    sh.x = (short)(xp.x >> 16); sl.x = (short)(xp.x & 0xffff);
    sh.y = (short)(xp.y >> 16); sl.y = (short)(xp.y & 0xffff);
    sh.z = (short)(xp.z >> 16); sl.z = (short)(xp.z & 0xffff);
    sh.w = (short)(xp.w >> 16); sl.w = (short)(xp.w & 0xffff);
    *(short4*)(xh_ + stb) = sh;
    *(short4*)(xl_ + stb) = sl;
}

template <bool LAST>
__global__ __launch_bounds__(512, 2) void lstm_kernel(
    const unsigned* __restrict__ xin, unsigned* __restrict__ yout,
    const float* __restrict__ Wih, const float* __restrict__ Whh,
    const float* __restrict__ bih, const float* __restrict__ bhh,
    const float* __restrict__ fcW, const float* __restrict__ fcb,
    float* __restrict__ out)
{
    __shared__ __align__(16) char xh_[4 * FRS];
    __shared__ __align__(16) char xl_[4 * FRS];
    __shared__ __align__(16) char hh_[4 * FRS];
    __shared__ __align__(16) char hl_[4 * FRS];
    __shared__ float fcp[32 * 17];

    const int tid = threadIdx.x;
    const int l   = tid & 63;
    const int w   = tid >> 6;
    const int l31 = l & 31;
    const int lh1 = l >> 5;
    const int s0  = blockIdx.x * 32;

    // weight A-fragments (hi/lo); row j via gate/unit remap
    bf16x8 wiH[4], wiL[4], whH[4], whL[4];
    {
        const int jg = ((l31 >> 3) << 6) + w * 8 + (l31 & 7);
#pragma unroll
        for (int ks = 0; ks < 4; ++ks) {
            int k0 = ks * 16 + lh1 * 8;
            float v[8];
            *(float4*)&v[0] = *(const float4*)&Wih[(size_t)jg * 64 + k0];
            *(float4*)&v[4] = *(const float4*)&Wih[(size_t)jg * 64 + k0 + 4];
            split8(v, wiH[ks], wiL[ks]);
            *(float4*)&v[0] = *(const float4*)&Whh[(size_t)jg * 64 + k0];
            *(float4*)&v[4] = *(const float4*)&Whh[(size_t)jg * 64 + k0 + 4];
            split8(v, whH[ks], whL[ks]);
        }
    }
    float bias_r[16];
#pragma unroll
    for (int r = 0; r < 16; ++r) {
        int j = ((r >> 2) << 6) + w * 8 + (r & 3) + 4 * lh1;
        bias_r[r] = bih[j] + bhh[j];
    }
    float fw[4];
    if constexpr (LAST) {
#pragma unroll
        for (int i = 0; i < 4; ++i) fw[i] = fcW[w * 8 + 4 * lh1 + i];
    }

    for (int i = tid; i < 4 * FRS / 4; i += 512) {
        ((int*)hh_)[i] = 0;
        ((int*)hl_)[i] = 0;
    }

    const int sm = tid >> 4;
    const int sk = (tid & 15) * 4;
    const unsigned stb = (unsigned)((sk >> 4) * FRS + ((((sk >> 3) & 1) << 5) + sm) * 16 + (sk & 7) * 2);
    const unsigned hwb = (unsigned)((w >> 1) * FRS + (((w & 1) << 5) + l31) * 16 + lh1 * 8);

    float cst[4] = {0.f, 0.f, 0.f, 0.f};
    float hfin[4] = {0.f, 0.f, 0.f, 0.f};

    // prologue: stage x(0)
    {
        uint4 xp = *(const uint4*)&xin[((size_t)(s0 + sm) * Tt + 0) * 64 + sk];
        stage_x(xp, stb, xh_, xl_);
    }
    __syncthreads();

    for (int t = 0; t < Tt; ++t) {
        // issue next-x load early; consumed after the post-cell barrier
        uint4 xq;
        if (t < Tt - 1)
            xq = *(const uint4*)&xin[((size_t)(s0 + sm) * Tt + (t + 1)) * 64 + sk];

        // 4 independent MFMA chains: x even/odd ks, h even/odd ks
        f32x16 p0, p1, q0, q1;
#pragma unroll
        for (int r = 0; r < 16; ++r) { p0[r] = 0.f; p1[r] = 0.f; q0[r] = 0.f; q1[r] = 0.f; }

#define LSTEP(KS, PX, QX)                                                        \
        {                                                                        \
            bf16x8 xh = *(bf16x8*)(xh_ + (KS) * FRS + l * 16);                   \
            bf16x8 xl = *(bf16x8*)(xl_ + (KS) * FRS + l * 16);                   \
            PX = __builtin_amdgcn_mfma_f32_32x32x16_bf16(wiH[KS], xh, PX, 0, 0, 0); \
            PX = __builtin_amdgcn_mfma_f32_32x32x16_bf16(wiL[KS], xh, PX, 0, 0, 0); \
            PX = __builtin_amdgcn_mfma_f32_32x32x16_bf16(wiH[KS], xl, PX, 0, 0, 0); \
            bf16x8 hh = *(bf16x8*)(hh_ + (KS) * FRS + l * 16);                   \
            bf16x8 hl = *(bf16x8*)(hl_ + (KS) * FRS + l * 16);                   \
            QX = __builtin_amdgcn_mfma_f32_32x32x16_bf16(whH[KS], hh, QX, 0, 0, 0); \
            QX = __builtin_amdgcn_mfma_f32_32x32x16_bf16(whL[KS], hh, QX, 0, 0, 0); \
            QX = __builtin_amdgcn_mfma_f32_32x32x16_bf16(whH[KS], hl, QX, 0, 0, 0); \
        }
        LSTEP(0, p0, q0)
        LSTEP(1, p1, q1)
        LSTEP(2, p0, q0)
        LSTEP(3, p1, q1)
#undef LSTEP

        // cell: per-lane, seq m = l31, units w*8 + 4*lh1 + {0..3}
        short4 nh, nl;
        unsigned yq[4];
#pragma unroll
        for (int ui = 0; ui < 4; ++ui) {
            float gi = p0[ui]      + p1[ui]      + q0[ui]      + q1[ui]      + bias_r[ui];
            float gf = p0[4 + ui]  + p1[4 + ui]  + q0[4 + ui]  + q1[4 + ui]  + bias_r[4 + ui];
            float gg = p0[8 + ui]  + p1[8 + ui]  + q0[8 + ui]  + q1[8 + ui]  + bias_r[8 + ui];
            float go = p0[12 + ui] + p1[12 + ui] + q0[12 + ui] + q1[12 + ui] + bias_r[12 + ui];
            float c  = sigf(gf) * cst[ui] + sigf(gi) * tanhfast(gg);
            float hv = sigf(go) * tanhfast(c);
            cst[ui] = c;
            unsigned short hb = f2bf(hv);
            unsigned short lb = f2bf(hv - bf2f(hb));
            ((short*)&nh)[ui] = (short)hb;
            ((short*)&nl)[ui] = (short)lb;
            if constexpr (!LAST) {
                yq[ui] = ((unsigned)hb << 16) | (unsigned)lb;
            } else {
                if (t == Tt - 1) hfin[ui] = hv;
            }
        }
        if constexpr (!LAST) {
            *(uint4*)&yout[((size_t)(s0 + l31) * Tt + t) * 64 + w * 8 + 4 * lh1] =
                make_uint4(yq[0], yq[1], yq[2], yq[3]);
        }
        __syncthreads();   // all waves done reading x,h; xq has drained
        if (t < Tt - 1) {
            stage_x(xq, stb, xh_, xl_);
            *(short4*)(hh_ + hwb) = nh;
            *(short4*)(hl_ + hwb) = nl;
        }
        __syncthreads();   // writes visible for next t
    }

    if constexpr (LAST) {
        float part = hfin[0] * fw[0] + hfin[1] * fw[1] + hfin[2] * fw[2] + hfin[3] * fw[3];
        fcp[l31 * 17 + w * 2 + lh1] = part;
        __syncthreads();
        if (tid < 32) {
            float s = fcb[0];
#pragma unroll
            for (int i = 0; i < 16; ++i) s += fcp[tid * 17 + i];
            out[s0 + tid] = s;
        }
    }
}

// ---------------------------------------------------------------------------
extern "C" void kernel_launch(void* const* d_in, const int* in_sizes, int n_in,
                              void* d_out, int out_size, void* d_ws, size_t ws_size,
                              hipStream_t stream) {
    const float* X      = (const float*)d_in[0];
    const float* adj    = (const float*)d_in[1];
    const float* gcn1_W = (const float*)d_in[2];
    const float* gcn1_b = (const float*)d_in[3];
    const float* gcn2_W = (const float*)d_in[4];
    const float* gcn2_b = (const float*)d_in[5];
    const float* Wih0   = (const float*)d_in[6];
    const float* Whh0   = (const float*)d_in[7];
    const float* bih0   = (const float*)d_in[8];
    const float* bhh0   = (const float*)d_in[9];
    const float* Wih1   = (const float*)d_in[10];
    const float* Whh1   = (const float*)d_in[11];
    const float* bih1   = (const float*)d_in[12];
    const float* bhh1   = (const float*)d_in[13];
    const float* fc_W   = (const float*)d_in[14];
    const float* fc_b   = (const float*)d_in[15];

    char* base = (char*)d_ws;
    float*    S      = (float*)base;                                   // 2 MB
    unsigned* buf0   = (unsigned*)(base + (size_t)BT * Nn * 4);        // 134 MB packed
    short*    adjPhi = (short*)(base + (size_t)BT * Nn * 4 + (size_t)Mseq * Tt * LH * 4);
    short*    adjPlo = adjPhi + 32768 * 8;                             // 512 KB each

    // A: S = X * adj^T  (fp32)
    sgemm_kernel<<<dim3(Nn / 64, BT / 64), 256, 0, stream>>>(X, adj, S);
    // P: adj -> PI-permuted fragment-major bf16 hi/lo
    adjpack_kernel<<<128, 256, 0, stream>>>(adj, adjPhi, adjPlo);
    // G: fused GCN (register z) -> buf0 (packed bf16 pairs, [m][t][h])
    gcnz_kernel<<<2048, 256, 0, stream>>>(
        S, adjPhi, adjPlo, gcn1_W, gcn1_b, gcn2_W, gcn2_b, buf0);
    // L0: LSTM layer 0, in-place on buf0
    lstm_kernel<false><<<Mseq / 32, 512, 0, stream>>>(
        buf0, buf0, Wih0, Whh0, bih0, bhh0, nullptr, nullptr, nullptr);
    // L1: LSTM layer 1 + FC -> d_out
    lstm_kernel<true><<<Mseq / 32, 512, 0, stream>>>(
        buf0, nullptr, Wih1, Whh1, bih1, bhh1, fc_W, fc_b, (float*)d_out);
}